// Round 1
// baseline (414.680 us; speedup 1.0000x reference)
//
#include <hip/hip_runtime.h>

#define B_ 8
#define C_ 32
#define H_ 512
#define W_ 512
#define HW_ (H_ * W_)
#define BN_EPS 1e-5f

// ws layout: float sums[8] = {sum[o=0..3], sumsq[o=0..3]}

__global__ __launch_bounds__(256) void fourdir_compute(
    const float* __restrict__ x,
    const float* __restrict__ w,
    float* __restrict__ y,
    float* __restrict__ sums)
{
    // Weight LDS: wl4[d][c] = float4 over o (d: 0=ne,1=nw,2=se,3=sw,4=center)
    __shared__ float4 wl4[5][C_];
    const int t = threadIdx.x;
    {
        float* wl = (float*)wl4;
        // wl[(d*C + c)*4 + o] = w[o*4C + d*C + c]; 512 elements, 2 per thread
        for (int idx = t; idx < 4 * 4 * C_; idx += 256) {
            int o  = idx & 3;
            int dc = idx >> 2;
            wl[idx] = w[o * (4 * C_) + dc];
        }
    }
    __syncthreads();
    if (t < 4 * C_) {
        float* wl = (float*)wl4;
        // center(c,o) at wl[512 + t], t = c*4+o; dir d at wl[d*128 + t]
        wl[512 + t] = -(wl[t] + wl[128 + t] + wl[256 + t] + wl[384 + t]);
    }
    __syncthreads();

    const int j     = (blockIdx.x << 6) + (t & 63);
    const int strip = t >> 6;
    const int i0    = (blockIdx.y << 4) + (strip << 2);
    const int b     = blockIdx.z;

    const float* xb = x + (size_t)b * C_ * HW_;
    const bool jm = (j > 0), jp = (j < W_ - 1);

    float4 acc[4];
#pragma unroll
    for (int p = 0; p < 4; ++p) acc[p] = make_float4(0.f, 0.f, 0.f, 0.f);

    for (int c = 0; c < C_; ++c) {
        const float* xc = xb + (size_t)c * HW_;
        float xl[6], xr[6], xm[4];
#pragma unroll
        for (int k = 0; k < 6; ++k) {
            const int r = i0 - 1 + k;
            const bool rv = (r >= 0) && (r < H_);
            const long off = (long)r * W_ + j;
            xl[k] = (rv && jm) ? xc[off - 1] : 0.f;
            xr[k] = (rv && jp) ? xc[off + 1] : 0.f;
        }
#pragma unroll
        for (int k = 0; k < 4; ++k) xm[k] = xc[(size_t)(i0 + k) * W_ + j];

        const float4 wne = wl4[0][c];
        const float4 wnw = wl4[1][c];
        const float4 wse = wl4[2][c];
        const float4 wsw = wl4[3][c];
        const float4 wct = wl4[4][c];
#pragma unroll
        for (int p = 0; p < 4; ++p) {
            // pixel row i0+p: north = idx p, south = idx p+2
            acc[p].x += wne.x * xr[p] + wnw.x * xl[p] + wse.x * xr[p + 2] + wsw.x * xl[p + 2] + wct.x * xm[p];
            acc[p].y += wne.y * xr[p] + wnw.y * xl[p] + wse.y * xr[p + 2] + wsw.y * xl[p + 2] + wct.y * xm[p];
            acc[p].z += wne.z * xr[p] + wnw.z * xl[p] + wse.z * xr[p + 2] + wsw.z * xl[p + 2] + wct.z * xm[p];
            acc[p].w += wne.w * xr[p] + wnw.w * xl[p] + wse.w * xr[p + 2] + wsw.w * xl[p + 2] + wct.w * xm[p];
        }
    }

    // Write y = [B][4][H][W]
#pragma unroll
    for (int p = 0; p < 4; ++p) {
        const size_t row = (size_t)(i0 + p) * W_ + j;
        y[((size_t)b * 4 + 0) * HW_ + row] = acc[p].x;
        y[((size_t)b * 4 + 1) * HW_ + row] = acc[p].y;
        y[((size_t)b * 4 + 2) * HW_ + row] = acc[p].z;
        y[((size_t)b * 4 + 3) * HW_ + row] = acc[p].w;
    }

    // Block reduction of sum / sumsq per output channel
    float vals[8];
    vals[0] = acc[0].x + acc[1].x + acc[2].x + acc[3].x;
    vals[1] = acc[0].y + acc[1].y + acc[2].y + acc[3].y;
    vals[2] = acc[0].z + acc[1].z + acc[2].z + acc[3].z;
    vals[3] = acc[0].w + acc[1].w + acc[2].w + acc[3].w;
    vals[4] = acc[0].x * acc[0].x + acc[1].x * acc[1].x + acc[2].x * acc[2].x + acc[3].x * acc[3].x;
    vals[5] = acc[0].y * acc[0].y + acc[1].y * acc[1].y + acc[2].y * acc[2].y + acc[3].y * acc[3].y;
    vals[6] = acc[0].z * acc[0].z + acc[1].z * acc[1].z + acc[2].z * acc[2].z + acc[3].z * acc[3].z;
    vals[7] = acc[0].w * acc[0].w + acc[1].w * acc[1].w + acc[2].w * acc[2].w + acc[3].w * acc[3].w;

#pragma unroll
    for (int k = 0; k < 8; ++k) {
        float v = vals[k];
#pragma unroll
        for (int off = 32; off >= 1; off >>= 1) v += __shfl_xor(v, off, 64);
        vals[k] = v;
    }

    __shared__ float red[4][8];
    const int wave = t >> 6;
    const int lane = t & 63;
    if (lane == 0) {
#pragma unroll
        for (int k = 0; k < 8; ++k) red[wave][k] = vals[k];
    }
    __syncthreads();
    if (t < 8) {
        const float s = red[0][t] + red[1][t] + red[2][t] + red[3][t];
        atomicAdd(&sums[t], s);
    }
}

__global__ __launch_bounds__(256) void bn_norm(
    float* __restrict__ y,
    const float* __restrict__ sums,
    const float* __restrict__ gamma,
    const float* __restrict__ beta)
{
    const int gid = blockIdx.x * 256 + threadIdx.x;       // float4 index
    const size_t base = (size_t)gid * 4;
    const int o = (int)((base / HW_) & 3);                // plane = b*4+o

    const float n = (float)((size_t)B_ * HW_);
    const float mean  = sums[o] / n;
    const float var   = sums[4 + o] / n - mean * mean;
    const float scale = rsqrtf(var + BN_EPS) * gamma[o];
    const float shift = beta[o] - mean * scale;

    float4 v = *(const float4*)(y + base);
    v.x = v.x * scale + shift;
    v.y = v.y * scale + shift;
    v.z = v.z * scale + shift;
    v.w = v.w * scale + shift;
    *(float4*)(y + base) = v;
}

extern "C" void kernel_launch(void* const* d_in, const int* in_sizes, int n_in,
                              void* d_out, int out_size, void* d_ws, size_t ws_size,
                              hipStream_t stream) {
    const float* x     = (const float*)d_in[0];
    const float* w     = (const float*)d_in[1];
    const float* gamma = (const float*)d_in[2];
    const float* beta  = (const float*)d_in[3];
    float* out  = (float*)d_out;
    float* sums = (float*)d_ws;

    // ws is poisoned 0xAA before every launch — zero the accumulators
    hipMemsetAsync(sums, 0, 8 * sizeof(float), stream);

    dim3 gridA(W_ / 64, H_ / 16, B_);
    fourdir_compute<<<gridA, 256, 0, stream>>>(x, w, out, sums);

    const int nf4 = (B_ * 4 * HW_) / 4;   // 2,097,152 float4s
    bn_norm<<<nf4 / 256, 256, 0, stream>>>(out, sums, gamma, beta);
}

// Round 2
// 395.721 us; speedup vs baseline: 1.0479x; 1.0479x over previous
//
#include <hip/hip_runtime.h>

#define B_ 8
#define C_ 32
#define H_ 512
#define W_ 512
#define HW_ (H_ * W_)
#define BN_EPS 1e-5f

// ws layout: float sums[8] = {sum[o=0..3], sumsq[o=0..3]}

typedef float f4v __attribute__((ext_vector_type(4)));

// Per-thread tile: 4 rows x 2 cols. Needs x cols j0-1..j0+2 (one dwordx4 at
// jb=j0-1, 4B-aligned — legal on gfx950 global loads) over rows i0-1..i0+4.
// EDGE=true path (blockIdx.x == 0 or 7) clamps jb and remaps for image edges.
template <bool EDGE>
__device__ __forceinline__ void conv_body(
    const float* __restrict__ xb, const float4 (*__restrict__ wl4)[C_],
    int i0, int j0, float acc[4][2][4])
{
    int jb = j0 - 1;
    bool le = false, re = false;
    if (EDGE) {
        le = (j0 == 0);
        re = (j0 == W_ - 2);
        if (le) jb = 0;
        if (re) jb = W_ - 4;
    }
    const bool rv0 = (i0 > 0);
    const bool rv5 = (i0 + 4 < H_);
    const int rows[6] = {rv0 ? i0 - 1 : 0, i0, i0 + 1, i0 + 2, i0 + 3,
                         rv5 ? i0 + 4 : H_ - 1};
    int off[6];
#pragma unroll
    for (int k = 0; k < 6; ++k) off[k] = rows[k] * W_ + jb;

    for (int c = 0; c < C_; ++c) {
        const float* xc = xb + (size_t)c * HW_;
        float v[6][4];
#pragma unroll
        for (int k = 0; k < 6; ++k) {
            f4v ld;
            __builtin_memcpy(&ld, xc + off[k], 16);   // align-4 dwordx4
            float a0 = ld.x, a1 = ld.y, a2 = ld.z, a3 = ld.w;
            if (EDGE) {
                if (le) { a0 = 0.f; a1 = ld.x; a2 = ld.y; a3 = ld.z; }
                if (re) { a0 = ld.y; a1 = ld.z; a2 = ld.w; a3 = 0.f; }
            }
            v[k][0] = a0; v[k][1] = a1; v[k][2] = a2; v[k][3] = a3;
        }
        if (!rv0) { v[0][0] = v[0][1] = v[0][2] = v[0][3] = 0.f; }
        if (!rv5) { v[5][0] = v[5][1] = v[5][2] = v[5][3] = 0.f; }

        const float4 wne = wl4[0][c];
        const float4 wnw = wl4[1][c];
        const float4 wse = wl4[2][c];
        const float4 wsw = wl4[3][c];
        const float4 wct = wl4[4][c];
        const float wneA[4] = {wne.x, wne.y, wne.z, wne.w};
        const float wnwA[4] = {wnw.x, wnw.y, wnw.z, wnw.w};
        const float wseA[4] = {wse.x, wse.y, wse.z, wse.w};
        const float wswA[4] = {wsw.x, wsw.y, wsw.z, wsw.w};
        const float wctA[4] = {wct.x, wct.y, wct.z, wct.w};

#pragma unroll
        for (int p = 0; p < 4; ++p)
#pragma unroll
            for (int q = 0; q < 2; ++q) {
                const float ne = v[p][q + 2];
                const float nw = v[p][q];
                const float se = v[p + 2][q + 2];
                const float sw = v[p + 2][q];
                const float ct = v[p + 1][q + 1];
#pragma unroll
                for (int o = 0; o < 4; ++o)
                    acc[p][q][o] += wneA[o] * ne + wnwA[o] * nw +
                                    wseA[o] * se + wswA[o] * sw + wctA[o] * ct;
            }
    }
}

__global__ __launch_bounds__(256) void fourdir_compute(
    const float* __restrict__ x,
    const float* __restrict__ w,
    float* __restrict__ y,
    float* __restrict__ sums)
{
    // Weight LDS: wl4[d][c] = float4 over o (d: 0=ne,1=nw,2=se,3=sw,4=center)
    __shared__ float4 wl4[5][C_];
    const int t = threadIdx.x;
    {
        float* wl = (float*)wl4;
        for (int idx = t; idx < 4 * 4 * C_; idx += 256) {
            int o  = idx & 3;
            int dc = idx >> 2;
            wl[idx] = w[o * (4 * C_) + dc];
        }
    }
    __syncthreads();
    if (t < 4 * C_) {
        float* wl = (float*)wl4;
        wl[512 + t] = -(wl[t] + wl[128 + t] + wl[256 + t] + wl[384 + t]);
    }
    __syncthreads();

    const int cg    = t & 31;         // col group (2 cols each)
    const int strip = t >> 5;         // row strip (4 rows each)
    const int j0 = (blockIdx.x << 6) + (cg << 1);
    const int i0 = (blockIdx.y << 5) + (strip << 2);
    const int b  = blockIdx.z;
    const float* xb = x + (size_t)b * C_ * HW_;

    float acc[4][2][4];
#pragma unroll
    for (int p = 0; p < 4; ++p)
#pragma unroll
        for (int q = 0; q < 2; ++q)
#pragma unroll
            for (int o = 0; o < 4; ++o) acc[p][q][o] = 0.f;

    if (blockIdx.x == 0 || blockIdx.x == (W_ / 64) - 1)
        conv_body<true>(xb, wl4, i0, j0, acc);
    else
        conv_body<false>(xb, wl4, i0, j0, acc);

    // Write y = [B][4][H][W], float2 per (row, o-plane)
#pragma unroll
    for (int p = 0; p < 4; ++p) {
        const size_t base = (size_t)(i0 + p) * W_ + j0;
#pragma unroll
        for (int o = 0; o < 4; ++o) {
            *(float2*)(y + ((size_t)(b * 4 + o)) * HW_ + base) =
                make_float2(acc[p][0][o], acc[p][1][o]);
        }
    }

    // Block reduction of sum / sumsq per output channel
    float vals[8];
#pragma unroll
    for (int o = 0; o < 4; ++o) { vals[o] = 0.f; vals[4 + o] = 0.f; }
#pragma unroll
    for (int p = 0; p < 4; ++p)
#pragma unroll
        for (int q = 0; q < 2; ++q)
#pragma unroll
            for (int o = 0; o < 4; ++o) {
                const float a = acc[p][q][o];
                vals[o]     += a;
                vals[4 + o] += a * a;
            }

#pragma unroll
    for (int k = 0; k < 8; ++k) {
        float v = vals[k];
#pragma unroll
        for (int off = 32; off >= 1; off >>= 1) v += __shfl_xor(v, off, 64);
        vals[k] = v;
    }

    __shared__ float red[4][8];
    const int wave = t >> 6;
    const int lane = t & 63;
    if (lane == 0) {
#pragma unroll
        for (int k = 0; k < 8; ++k) red[wave][k] = vals[k];
    }
    __syncthreads();
    if (t < 8) {
        const float s = red[0][t] + red[1][t] + red[2][t] + red[3][t];
        atomicAdd(&sums[t], s);
    }
}

__global__ __launch_bounds__(256) void bn_norm(
    float* __restrict__ y,
    const float* __restrict__ sums,
    const float* __restrict__ gamma,
    const float* __restrict__ beta)
{
    const int gid = blockIdx.x * 256 + threadIdx.x;       // float4 index
    const size_t base = (size_t)gid * 4;
    const int o = (int)((base / HW_) & 3);                // plane = b*4+o

    const float n = (float)((size_t)B_ * HW_);
    const float mean  = sums[o] / n;
    const float var   = sums[4 + o] / n - mean * mean;
    const float scale = rsqrtf(var + BN_EPS) * gamma[o];
    const float shift = beta[o] - mean * scale;

    float4 v = *(const float4*)(y + base);
    v.x = v.x * scale + shift;
    v.y = v.y * scale + shift;
    v.z = v.z * scale + shift;
    v.w = v.w * scale + shift;
    *(float4*)(y + base) = v;
}

extern "C" void kernel_launch(void* const* d_in, const int* in_sizes, int n_in,
                              void* d_out, int out_size, void* d_ws, size_t ws_size,
                              hipStream_t stream) {
    const float* x     = (const float*)d_in[0];
    const float* w     = (const float*)d_in[1];
    const float* gamma = (const float*)d_in[2];
    const float* beta  = (const float*)d_in[3];
    float* out  = (float*)d_out;
    float* sums = (float*)d_ws;

    // ws is poisoned 0xAA before every launch — zero the accumulators
    hipMemsetAsync(sums, 0, 8 * sizeof(float), stream);

    dim3 gridA(W_ / 64, H_ / 32, B_);   // 8 x 16 x 8 = 1024 blocks
    fourdir_compute<<<gridA, 256, 0, stream>>>(x, w, out, sums);

    const int nf4 = (B_ * 4 * HW_) / 4;   // 2,097,152 float4s
    bn_norm<<<nf4 / 256, 256, 0, stream>>>(out, sums, gamma, beta);
}

// Round 3
// 394.363 us; speedup vs baseline: 1.0515x; 1.0034x over previous
//
#include <hip/hip_runtime.h>

#define B_ 8
#define C_ 32
#define H_ 512
#define W_ 512
#define HW_ (H_ * W_)
#define BN_EPS 1e-5f

typedef float f4v __attribute__((ext_vector_type(4)));

// ws layout: float sums[8] = {sum[o=0..3], sumsq[o=0..3]}

__global__ __launch_bounds__(256, 2) void fourdir_compute(
    const float* __restrict__ x,
    const float* __restrict__ w,
    float* __restrict__ y,
    float* __restrict__ sums)
{
    // Weight LDS: wl4[d][c] = float4 over o (d: 0=ne,1=nw,2=se,3=sw,4=center)
    __shared__ f4v wl4[5][C_];
    const int t = threadIdx.x;
    {
        float* wl = (float*)wl4;
        for (int idx = t; idx < 4 * 4 * C_; idx += 256) {
            int o  = idx & 3;
            int dc = idx >> 2;
            wl[idx] = w[o * (4 * C_) + dc];
        }
    }
    __syncthreads();
    if (t < 4 * C_) {
        float* wl = (float*)wl4;
        wl[512 + t] = -(wl[t] + wl[128 + t] + wl[256 + t] + wl[384 + t]);
    }
    __syncthreads();

    // Thread tile: 4 rows x 4 cols. Block tile: 64 rows x 64 cols.
    const int lane = t & 63;
    const int wv   = t >> 6;
    const int cg   = lane & 15;   // 16 col-groups * 4 cols = 64 cols
    const int sr   = lane >> 4;   // 4 row-strips * 4 rows = 16 rows / wave
    const int j0 = (blockIdx.x << 6) + (cg << 2);
    const int i0 = (blockIdx.y << 6) + (wv << 4) + (sr << 2);
    const int b  = blockIdx.z;
    const float* xb = x + (size_t)b * C_ * HW_;

    const bool jm = (j0 > 0);          // left halo col exists
    const bool jp = (j0 + 4 < W_);     // right halo col exists
    const bool tv = (i0 > 0);          // top halo row exists
    const bool bv = (i0 + 4 < H_);     // bottom halo row exists

    int off[6];
    {
        const int rows[6] = { tv ? i0 - 1 : 0, i0, i0 + 1, i0 + 2, i0 + 3,
                              bv ? i0 + 4 : H_ - 1 };
#pragma unroll
        for (int k = 0; k < 6; ++k) off[k] = rows[k] * W_ + j0;
    }

    f4v acc[4][4];
#pragma unroll
    for (int p = 0; p < 4; ++p)
#pragma unroll
        for (int q = 0; q < 4; ++q) acc[p][q] = f4v{0.f, 0.f, 0.f, 0.f};

#pragma unroll 2
    for (int c = 0; c < C_; ++c) {
        const float* xc = xb + (size_t)c * HW_;
        f4v  vr[6];
        float lf[6], rt[6];
#pragma unroll
        for (int k = 0; k < 6; ++k) {
            vr[k] = *(const f4v*)(xc + off[k]);        // 16B-aligned dwordx4
            lf[k] = jm ? xc[off[k] - 1] : 0.f;          // L1-hit halo
            rt[k] = jp ? xc[off[k] + 4] : 0.f;
        }
        if (!tv) { vr[0] = f4v{0.f,0.f,0.f,0.f}; lf[0] = 0.f; rt[0] = 0.f; }
        if (!bv) { vr[5] = f4v{0.f,0.f,0.f,0.f}; lf[5] = 0.f; rt[5] = 0.f; }

        const f4v wne = wl4[0][c];
        const f4v wnw = wl4[1][c];
        const f4v wse = wl4[2][c];
        const f4v wsw = wl4[3][c];
        const f4v wct = wl4[4][c];

#pragma unroll
        for (int p = 0; p < 4; ++p) {
#pragma unroll
            for (int q = 0; q < 4; ++q) {
                const float ne = (q < 3) ? vr[p][q + 1]     : rt[p];
                const float nw = (q > 0) ? vr[p][q - 1]     : lf[p];
                const float se = (q < 3) ? vr[p + 2][q + 1] : rt[p + 2];
                const float sw = (q > 0) ? vr[p + 2][q - 1] : lf[p + 2];
                const float ct = vr[p + 1][q];
                acc[p][q] += wne * ne + wnw * nw + wse * se + wsw * sw + wct * ct;
            }
        }
    }

    // Write y = [B][4][H][W], aligned float4 per (row, o-plane)
#pragma unroll
    for (int p = 0; p < 4; ++p) {
        const size_t base = (size_t)(i0 + p) * W_ + j0;
#pragma unroll
        for (int o = 0; o < 4; ++o) {
            f4v st = { acc[p][0][o], acc[p][1][o], acc[p][2][o], acc[p][3][o] };
            *(f4v*)(y + ((size_t)(b * 4 + o)) * HW_ + base) = st;
        }
    }

    // Block reduction of sum / sumsq per output channel
    f4v s0 = f4v{0.f,0.f,0.f,0.f}, s1 = f4v{0.f,0.f,0.f,0.f};
#pragma unroll
    for (int p = 0; p < 4; ++p)
#pragma unroll
        for (int q = 0; q < 4; ++q) {
            s0 += acc[p][q];
            s1 += acc[p][q] * acc[p][q];
        }

    float vals[8] = { s0[0], s0[1], s0[2], s0[3], s1[0], s1[1], s1[2], s1[3] };
#pragma unroll
    for (int k = 0; k < 8; ++k) {
        float v = vals[k];
#pragma unroll
        for (int o = 32; o >= 1; o >>= 1) v += __shfl_xor(v, o, 64);
        vals[k] = v;
    }

    __shared__ float red[4][8];
    if (lane == 0) {
#pragma unroll
        for (int k = 0; k < 8; ++k) red[wv][k] = vals[k];
    }
    __syncthreads();
    if (t < 8) {
        const float s = red[0][t] + red[1][t] + red[2][t] + red[3][t];
        atomicAdd(&sums[t], s);
    }
}

__global__ __launch_bounds__(256) void bn_norm(
    float* __restrict__ y,
    const float* __restrict__ sums,
    const float* __restrict__ gamma,
    const float* __restrict__ beta)
{
    const int gid = blockIdx.x * 256 + threadIdx.x;       // float4 index
    const size_t base = (size_t)gid * 4;
    const int o = (int)((base / HW_) & 3);                // plane = b*4+o

    const float n = (float)((size_t)B_ * HW_);
    const float mean  = sums[o] / n;
    const float var   = sums[4 + o] / n - mean * mean;
    const float scale = rsqrtf(var + BN_EPS) * gamma[o];
    const float shift = beta[o] - mean * scale;

    float4 v = *(const float4*)(y + base);
    v.x = v.x * scale + shift;
    v.y = v.y * scale + shift;
    v.z = v.z * scale + shift;
    v.w = v.w * scale + shift;
    *(float4*)(y + base) = v;
}

extern "C" void kernel_launch(void* const* d_in, const int* in_sizes, int n_in,
                              void* d_out, int out_size, void* d_ws, size_t ws_size,
                              hipStream_t stream) {
    const float* x     = (const float*)d_in[0];
    const float* w     = (const float*)d_in[1];
    const float* gamma = (const float*)d_in[2];
    const float* beta  = (const float*)d_in[3];
    float* out  = (float*)d_out;
    float* sums = (float*)d_ws;

    // ws is poisoned 0xAA before every launch — zero the accumulators
    hipMemsetAsync(sums, 0, 8 * sizeof(float), stream);

    dim3 gridA(W_ / 64, H_ / 64, B_);   // 8 x 8 x 8 = 512 blocks (2/CU)
    fourdir_compute<<<gridA, 256, 0, stream>>>(x, w, out, sums);

    const int nf4 = (B_ * 4 * HW_) / 4;   // 2,097,152 float4s
    bn_norm<<<nf4 / 256, 256, 0, stream>>>(out, sums, gamma, beta);
}